// Round 4
// baseline (630.885 us; speedup 1.0000x reference)
//
#include <hip/hip_runtime.h>
#include <hip/hip_bf16.h>
#include <hip/hip_cooperative_groups.h>
#include <math.h>

namespace cg = cooperative_groups;

#define N_NODES 20000
#define N_EDGES 200000
#define D_H 32
#define E_DIM 16
#define W2S_SHORTS (17 * 2 * 64 * 8)    // 17408 bf16: 17 K-steps x 2 tiles x 64 lanes x 8
#define PREP_SHORTS (W2S_SHORTS + 512)  // + w1/b1 fragment
#define GRID 512
#define BLK  512
#define NTHREADS (GRID * BLK)           // 262144
#define NWAVE (NTHREADS / 64)           // 4096
#define NTILES (N_EDGES / 16)           // 12500

typedef __attribute__((ext_vector_type(8))) short bf16x8;
typedef __attribute__((ext_vector_type(4))) float f32x4;

__device__ __forceinline__ float elu_f(float v) { return v > 0.f ? v : expm1f(v); }
__device__ __forceinline__ short f2bf(float f) {
    union { __hip_bfloat16 h; short s; } u;
    u.h = __float2bfloat16(f);
    return u.s;
}
__device__ __forceinline__ float bf2f(__hip_bfloat16 h) { return __bfloat162float(h); }

// ================= phase device functions (shared by mega + fallback) =================

// P0: zero deg + build bf16 weight fragments for both layers
__device__ __forceinline__ void p0_phase(
    const float* __restrict__ w2_0, const float* __restrict__ b2_0,
    const float* __restrict__ w1_0, const float* __restrict__ b1_0,
    const float* __restrict__ w2_1, const float* __restrict__ b2_1,
    const float* __restrict__ w1_1, const float* __restrict__ b1_1,
    int* __restrict__ deg, short* __restrict__ prep, int gid)
{
    if (gid < N_NODES) deg[gid] = 0;
    if (gid < 2 * PREP_SHORTS) {
        int layer = gid / PREP_SHORTS;
        int r = gid - layer * PREP_SHORTS;
        const float* w2 = layer ? w2_1 : w2_0;
        const float* b2 = layer ? b2_1 : b2_0;
        const float* w1 = layer ? w1_1 : w1_0;
        const float* b1 = layer ? b1_1 : b1_0;
        float v;
        if (r < W2S_SHORTS) {
            int j = r & 7, l = (r >> 3) & 63, tile = (r >> 9) & 1, kk = r >> 10;
            int ii = (l >> 4) * 8 + j;
            int o = tile * 16 + (l & 15);
            v = (kk < 16) ? w2[kk * 1024 + ii * 32 + o] : b2[ii * 32 + o];
        } else {
            int q = r - W2S_SHORTS;
            int j = q & 7, l = q >> 3;
            int k = (l >> 4) * 8 + j, n = l & 15;
            v = (k < 16) ? w1[k * 16 + n] : (k == 16 ? b1[n] : 0.f);
        }
        prep[gid] = f2bf(v);
    }
}

__device__ __forceinline__ void scan_phase(const int* __restrict__ deg,
                                           int* __restrict__ rowptr,
                                           int* __restrict__ cursor,
                                           int* part, int tid, int bid)
{
    if (bid != 0) return;
    const int base = tid * 40;
    int sum = 0;
    for (int j = 0; j < 40; ++j) {
        int idx = base + j;
        if (idx < N_NODES) sum += deg[idx];
    }
    part[tid] = sum;
    __syncthreads();
    for (int off = 1; off < BLK; off <<= 1) {
        int v = (tid >= off) ? part[tid - off] : 0;
        __syncthreads();
        part[tid] += v;
        __syncthreads();
    }
    int run = part[tid] - sum;
    for (int j = 0; j < 40; ++j) {
        int idx = base + j;
        if (idx < N_NODES) {
            int v = deg[idx];
            rowptr[idx] = run; cursor[idx] = run; run += v;
        }
    }
    if (tid == 0) rowptr[N_NODES] = N_EDGES;
}

// edge phase: per wave 16 edges; h via 1 MFMA (wave-private LDS transpose, no barrier);
// msg = (h,1) x W2'' via 34 MFMA with A from LDS, B = x-frag in regs; store row at pos[e].
__device__ __forceinline__ void edge_phase(
    const float* __restrict__ xin, const float* __restrict__ edge_attr,
    const int* __restrict__ src, const int* __restrict__ pos,
    const short* __restrict__ prepL, __hip_bfloat16* __restrict__ msg,
    short* w2s, float (*h_s)[16][20], int tid, int bid)
{
    for (int i = tid; i < PREP_SHORTS / 8; i += BLK)
        ((int4*)w2s)[i] = ((const int4*)prepL)[i];
    __syncthreads();

    const int lane = tid & 63;
    const int wave = tid >> 6;
    const int gw = bid * (BLK / 64) + wave;
    const int eloc = lane & 15;
    const int kg = lane >> 4;
    const f32x4 zero4 = {0.f, 0.f, 0.f, 0.f};

    for (int tile = gw; tile < NTILES; tile += NWAVE) {
        const int e = tile * 16 + eloc;
        const int sn = src[e];
        const int pe = pos[e];
        const float4 x0 = *(const float4*)(xin + (size_t)sn * 32 + kg * 8);
        const float4 x1 = *(const float4*)(xin + (size_t)sn * 32 + kg * 8 + 4);

        // edge-attr A-fragment: A[m=eloc][k=kg*8+j]; k=16 -> 1.0 (bias), else 0
        bf16x8 af = {0, 0, 0, 0, 0, 0, 0, 0};
        if (kg < 2) {
            const float4 a0 = *(const float4*)(edge_attr + (size_t)e * E_DIM + kg * 8);
            const float4 a1 = *(const float4*)(edge_attr + (size_t)e * E_DIM + kg * 8 + 4);
            af[0] = f2bf(a0.x); af[1] = f2bf(a0.y); af[2] = f2bf(a0.z); af[3] = f2bf(a0.w);
            af[4] = f2bf(a1.x); af[5] = f2bf(a1.y); af[6] = f2bf(a1.z); af[7] = f2bf(a1.w);
        } else if (kg == 2) {
            af[0] = f2bf(1.0f);
        }

        // h-MFMA: lane gets h[edge=kg*4+r][k=eloc]; exchange via wave-private LDS slice
        {
            bf16x8 w1f = *(const bf16x8*)&w2s[W2S_SHORTS + lane * 8];
            f32x4 hd = __builtin_amdgcn_mfma_f32_16x16x32_bf16(af, w1f, zero4, 0, 0, 0);
            #pragma unroll
            for (int r = 0; r < 4; ++r)
                h_s[wave][kg * 4 + r][eloc] = elu_f(hd[r]);
        }

        bf16x8 xb;
        xb[0] = f2bf(x0.x); xb[1] = f2bf(x0.y); xb[2] = f2bf(x0.z); xb[3] = f2bf(x0.w);
        xb[4] = f2bf(x1.x); xb[5] = f2bf(x1.y); xb[6] = f2bf(x1.z); xb[7] = f2bf(x1.w);

        // within-wave LDS ordering: ds ops of one wave execute in program order
        float hr[16];
        *(f32x4*)&hr[0]  = *(const f32x4*)&h_s[wave][eloc][0];
        *(f32x4*)&hr[4]  = *(const f32x4*)&h_s[wave][eloc][4];
        *(f32x4*)&hr[8]  = *(const f32x4*)&h_s[wave][eloc][8];
        *(f32x4*)&hr[12] = *(const f32x4*)&h_s[wave][eloc][12];

        float m0[4] = {0, 0, 0, 0}, m1[4] = {0, 0, 0, 0};
        #pragma unroll
        for (int kk = 0; kk < 16; ++kk) {
            bf16x8 a0 = *(const bf16x8*)&w2s[(kk * 2 + 0) * 512 + lane * 8];
            bf16x8 a1 = *(const bf16x8*)&w2s[(kk * 2 + 1) * 512 + lane * 8];
            f32x4 d0 = __builtin_amdgcn_mfma_f32_16x16x32_bf16(a0, xb, zero4, 0, 0, 0);
            f32x4 d1 = __builtin_amdgcn_mfma_f32_16x16x32_bf16(a1, xb, zero4, 0, 0, 0);
            const float hk = hr[kk];
            #pragma unroll
            for (int r = 0; r < 4; ++r) { m0[r] += hk * d0[r]; m1[r] += hk * d1[r]; }
        }
        {   // kk=16: b2 rows (h == 1)
            bf16x8 a0 = *(const bf16x8*)&w2s[(16 * 2 + 0) * 512 + lane * 8];
            bf16x8 a1 = *(const bf16x8*)&w2s[(16 * 2 + 1) * 512 + lane * 8];
            f32x4 d0 = __builtin_amdgcn_mfma_f32_16x16x32_bf16(a0, xb, zero4, 0, 0, 0);
            f32x4 d1 = __builtin_amdgcn_mfma_f32_16x16x32_bf16(a1, xb, zero4, 0, 0, 0);
            #pragma unroll
            for (int r = 0; r < 4; ++r) { m0[r] += d0[r]; m1[r] += d1[r]; }
        }

        // CSR-ordered store: row pe, coalesced-ish 8B chunks
        short* mp = (short*)(msg + (size_t)pe * D_H);
        short q0[4] = { f2bf(m0[0]), f2bf(m0[1]), f2bf(m0[2]), f2bf(m0[3]) };
        short q1[4] = { f2bf(m1[0]), f2bf(m1[1]), f2bf(m1[2]), f2bf(m1[3]) };
        *(int2*)(mp + kg * 4)      = *(int2*)q0;
        *(int2*)(mp + 16 + kg * 4) = *(int2*)q1;
    }
}

// agg: half-wave per node; contiguous CSR msg rows; root GEMM with x in regs; ELU;
// LAST: fused classifier via shuffles.
template<bool LAST>
__device__ __forceinline__ void agg_phase(
    const float* __restrict__ xin, const __hip_bfloat16* __restrict__ msg,
    const int* __restrict__ rowptr,
    const float* __restrict__ root, const float* __restrict__ bias,
    const float* __restrict__ cls_w, const float* __restrict__ cls_b,
    float* __restrict__ hout, float* __restrict__ out,
    float* root_s, float* bias_s, float* clsw_s, float* clsb_s,
    int tid, int bid)
{
    for (int i = tid; i < 1024; i += BLK) root_s[i] = root[i];
    if (tid < 32) bias_s[tid] = bias[tid];
    if (LAST) {
        if (tid < 256) clsw_s[tid] = cls_w[tid];
        if (tid < 8) clsb_s[tid] = cls_b[tid];
    }
    __syncthreads();

    const int lane = tid & 63;
    const int wave = tid >> 6;
    const int gw = bid * (BLK / 64) + wave;
    const int half = lane >> 5;
    const int o = lane & 31;

    for (int n = gw * 2 + half; n < N_NODES; n += NWAVE * 2) {
        const int start = rowptr[n], end = rowptr[n + 1];
        float s = 0.f;
        for (int j = start; j < end; ++j)
            s += bf2f(msg[(size_t)j * D_H + o]);
        float acc = s * (1.f / fmaxf((float)(end - start), 1.f)) + bias_s[o];

        float xr[32];
        #pragma unroll
        for (int q = 0; q < 8; ++q)
            *(float4*)&xr[q * 4] = *(const float4*)(xin + (size_t)n * 32 + q * 4);
        #pragma unroll
        for (int i = 0; i < 32; ++i)
            acc += xr[i] * root_s[i * 32 + o];
        acc = elu_f(acc);

        if (!LAST) {
            hout[(size_t)n * 32 + o] = acc;
        } else {
            float a = (o < 8) ? clsb_s[o] : 0.f;
            #pragma unroll
            for (int i = 0; i < 32; ++i) {
                float hi = __shfl(acc, half * 32 + i);
                if (o < 8) a += hi * clsw_s[i * 8 + o];
            }
            if (o < 8) out[(size_t)n * 8 + o] = a;
        }
    }
}

// ================= mega cooperative kernel =================
__global__ void __launch_bounds__(BLK, 4)
mega_kernel(const float* x, const float* edge_attr, const int* edge_index,
            const float* w1_0, const float* b1_0, const float* w2_0, const float* b2_0,
            const float* root_0, const float* bias_0,
            const float* w1_1, const float* b1_1, const float* w2_1, const float* b2_1,
            const float* root_1, const float* bias_1,
            const float* cls_w, const float* cls_b,
            int* deg, int* rowptr, int* cursor, int* pos,
            short* prep, __hip_bfloat16* msg, float* hbuf, float* out)
{
    __shared__ __align__(16) short w2s[PREP_SHORTS];
    __shared__ __align__(16) float h_s[8][16][20];
    __shared__ int part[BLK];
    __shared__ float root_s[1024], bias_s[32], clsw_s[256], clsb_s[8];

    cg::grid_group grid = cg::this_grid();
    const int tid = threadIdx.x, bid = blockIdx.x;
    const int gid = bid * BLK + tid;
    const int* src = edge_index;
    const int* dst = edge_index + N_EDGES;

    p0_phase(w2_0, b2_0, w1_0, b1_0, w2_1, b2_1, w1_1, b1_1, deg, prep, gid);
    grid.sync();

    for (int e = gid; e < N_EDGES; e += NTHREADS) atomicAdd(&deg[dst[e]], 1);
    grid.sync();

    scan_phase(deg, rowptr, cursor, part, tid, bid);
    grid.sync();

    for (int e = gid; e < N_EDGES; e += NTHREADS) pos[e] = atomicAdd(&cursor[dst[e]], 1);
    grid.sync();

    edge_phase(x, edge_attr, src, pos, prep, msg, w2s, h_s, tid, bid);
    grid.sync();

    agg_phase<false>(x, msg, rowptr, root_0, bias_0, nullptr, nullptr, hbuf, nullptr,
                     root_s, bias_s, clsw_s, clsb_s, tid, bid);
    grid.sync();

    edge_phase(hbuf, edge_attr, src, pos, prep + PREP_SHORTS, msg, w2s, h_s, tid, bid);
    grid.sync();

    agg_phase<true>(hbuf, msg, rowptr, root_1, bias_1, cls_w, cls_b, nullptr, out,
                    root_s, bias_s, clsw_s, clsb_s, tid, bid);
}

// ================= fallback wrappers (plain launches, same phase code) =================
__global__ void __launch_bounds__(BLK, 4)
k_p0(const float* w2_0, const float* b2_0, const float* w1_0, const float* b1_0,
     const float* w2_1, const float* b2_1, const float* w1_1, const float* b1_1,
     int* deg, short* prep)
{
    p0_phase(w2_0, b2_0, w1_0, b1_0, w2_1, b2_1, w1_1, b1_1, deg, prep,
             blockIdx.x * BLK + threadIdx.x);
}
__global__ void __launch_bounds__(BLK, 4)
k_deg(const int* edge_index, int* deg)
{
    const int* dst = edge_index + N_EDGES;
    for (int e = blockIdx.x * BLK + threadIdx.x; e < N_EDGES; e += NTHREADS)
        atomicAdd(&deg[dst[e]], 1);
}
__global__ void __launch_bounds__(BLK, 4)
k_scan(const int* deg, int* rowptr, int* cursor)
{
    __shared__ int part[BLK];
    scan_phase(deg, rowptr, cursor, part, threadIdx.x, blockIdx.x);
}
__global__ void __launch_bounds__(BLK, 4)
k_fill(const int* edge_index, int* cursor, int* pos)
{
    const int* dst = edge_index + N_EDGES;
    for (int e = blockIdx.x * BLK + threadIdx.x; e < N_EDGES; e += NTHREADS)
        pos[e] = atomicAdd(&cursor[dst[e]], 1);
}
__global__ void __launch_bounds__(BLK, 4)
k_edge(const float* xin, const float* edge_attr, const int* edge_index,
       const int* pos, const short* prepL, __hip_bfloat16* msg)
{
    __shared__ __align__(16) short w2s[PREP_SHORTS];
    __shared__ __align__(16) float h_s[8][16][20];
    edge_phase(xin, edge_attr, edge_index, pos, prepL, msg, w2s, h_s,
               threadIdx.x, blockIdx.x);
}
template<bool LAST>
__global__ void __launch_bounds__(BLK, 4)
k_agg(const float* xin, const __hip_bfloat16* msg, const int* rowptr,
      const float* root, const float* bias, const float* cls_w, const float* cls_b,
      float* hout, float* out)
{
    __shared__ float root_s[1024], bias_s[32], clsw_s[256], clsb_s[8];
    agg_phase<LAST>(xin, msg, rowptr, root, bias, cls_w, cls_b, hout, out,
                    root_s, bias_s, clsw_s, clsb_s, threadIdx.x, blockIdx.x);
}

extern "C" void kernel_launch(void* const* d_in, const int* in_sizes, int n_in,
                              void* d_out, int out_size, void* d_ws, size_t ws_size,
                              hipStream_t stream)
{
    const float* x          = (const float*)d_in[0];
    const float* edge_attr  = (const float*)d_in[1];
    const int*   edge_index = (const int*)d_in[2];
    const float* w1_0 = (const float*)d_in[3];
    const float* b1_0 = (const float*)d_in[4];
    const float* w2_0 = (const float*)d_in[5];
    const float* b2_0 = (const float*)d_in[6];
    const float* root_0 = (const float*)d_in[7];
    const float* bias_0 = (const float*)d_in[8];
    const float* w1_1 = (const float*)d_in[9];
    const float* b1_1 = (const float*)d_in[10];
    const float* w2_1 = (const float*)d_in[11];
    const float* b2_1 = (const float*)d_in[12];
    const float* root_1 = (const float*)d_in[13];
    const float* bias_1 = (const float*)d_in[14];
    const float* cls_w = (const float*)d_in[15];
    const float* cls_b = (const float*)d_in[16];

    char* ws = (char*)d_ws;
    int* deg    = (int*)ws;
    int* rowptr = deg + N_NODES;
    int* cursor = rowptr + N_NODES + 1;
    int* pos    = cursor + N_NODES;
    size_t off = ((size_t)(3 * N_NODES + 1 + N_EDGES) * 4 + 15) & ~(size_t)15;
    short* prep = (short*)(ws + off);
    off = (off + (size_t)2 * PREP_SHORTS * 2 + 15) & ~(size_t)15;
    __hip_bfloat16* msg = (__hip_bfloat16*)(ws + off);
    off = (off + (size_t)N_EDGES * D_H * 2 + 15) & ~(size_t)15;
    float* hbuf = (float*)(ws + off);
    float* out = (float*)d_out;

    void* args[] = {
        (void*)&x, (void*)&edge_attr, (void*)&edge_index,
        (void*)&w1_0, (void*)&b1_0, (void*)&w2_0, (void*)&b2_0,
        (void*)&root_0, (void*)&bias_0,
        (void*)&w1_1, (void*)&b1_1, (void*)&w2_1, (void*)&b2_1,
        (void*)&root_1, (void*)&bias_1,
        (void*)&cls_w, (void*)&cls_b,
        (void*)&deg, (void*)&rowptr, (void*)&cursor, (void*)&pos,
        (void*)&prep, (void*)&msg, (void*)&hbuf, (void*)&out
    };

    hipError_t err = hipLaunchCooperativeKernel((void*)mega_kernel,
                                                dim3(GRID), dim3(BLK),
                                                args, 0, stream);
    if (err != hipSuccess) {
        // fallback: same phases as separate kernels
        k_p0<<<GRID, BLK, 0, stream>>>(w2_0, b2_0, w1_0, b1_0, w2_1, b2_1, w1_1, b1_1,
                                       deg, prep);
        k_deg<<<GRID, BLK, 0, stream>>>(edge_index, deg);
        k_scan<<<GRID, BLK, 0, stream>>>(deg, rowptr, cursor);
        k_fill<<<GRID, BLK, 0, stream>>>(edge_index, cursor, pos);
        k_edge<<<GRID, BLK, 0, stream>>>(x, edge_attr, edge_index, pos, prep, msg);
        k_agg<false><<<GRID, BLK, 0, stream>>>(x, msg, rowptr, root_0, bias_0,
                                               nullptr, nullptr, hbuf, nullptr);
        k_edge<<<GRID, BLK, 0, stream>>>(hbuf, edge_attr, edge_index, pos,
                                         prep + PREP_SHORTS, msg);
        k_agg<true><<<GRID, BLK, 0, stream>>>(hbuf, msg, rowptr, root_1, bias_1,
                                              cls_w, cls_b, nullptr, out);
    }
}

// Round 5
// 129.672 us; speedup vs baseline: 4.8652x; 4.8652x over previous
//
#include <hip/hip_runtime.h>
#include <hip/hip_bf16.h>
#include <math.h>

#define N_NODES 20000
#define N_EDGES 200000
#define D_H 32
#define E_DIM 16
#define NTILES (N_EDGES / 16)           // 12500
#define W2S_SHORTS (17 * 2 * 64 * 8)    // 17408 bf16: 17 K-steps x 2 tiles x 64 lanes x 8
#define PREP_SHORTS (W2S_SHORTS + 512)  // + w1/b1 fragment = 17920

typedef __attribute__((ext_vector_type(8))) short bf16x8;
typedef __attribute__((ext_vector_type(4))) float f32x4;

__device__ __forceinline__ float elu_f(float v) { return v > 0.f ? v : expm1f(v); }
__device__ __forceinline__ short f2bf(float f) {
    union { __hip_bfloat16 h; short s; } u;
    u.h = __float2bfloat16(f);
    return u.s;
}
__device__ __forceinline__ float bf2f(__hip_bfloat16 h) { return __bfloat162float(h); }

// ---------------- init: zero deg + build bf16 weight fragments (both layers) ----------------
__global__ __launch_bounds__(256)
void init_kernel(const float* __restrict__ w2_0, const float* __restrict__ b2_0,
                 const float* __restrict__ w1_0, const float* __restrict__ b1_0,
                 const float* __restrict__ w2_1, const float* __restrict__ b2_1,
                 const float* __restrict__ w1_1, const float* __restrict__ b1_1,
                 int* __restrict__ deg, short* __restrict__ prep)
{
    const int gid = blockIdx.x * 256 + threadIdx.x;
    if (gid < N_NODES) deg[gid] = 0;
    if (gid < 2 * PREP_SHORTS) {
        int layer = gid >= PREP_SHORTS ? 1 : 0;
        int r = gid - layer * PREP_SHORTS;
        const float* w2 = layer ? w2_1 : w2_0;
        const float* b2 = layer ? b2_1 : b2_0;
        const float* w1 = layer ? w1_1 : w1_0;
        const float* b1 = layer ? b1_1 : b1_0;
        float v;
        if (r < W2S_SHORTS) {
            int j = r & 7, l = (r >> 3) & 63, tile = (r >> 9) & 1, kk = r >> 10;
            int ii = (l >> 4) * 8 + j;
            int o = tile * 16 + (l & 15);
            v = (kk < 16) ? w2[kk * 1024 + ii * 32 + o] : b2[ii * 32 + o];
        } else {
            int q = r - W2S_SHORTS;
            int j = q & 7, l = q >> 3;
            int k = (l >> 4) * 8 + j, n = l & 15;
            v = (k < 16) ? w1[k * 16 + n] : (k == 16 ? b1[n] : 0.f);
        }
        prep[gid] = f2bf(v);
    }
}

// ---------------- degree histogram ----------------
__global__ __launch_bounds__(256)
void deg_kernel(const int* __restrict__ dst, int* __restrict__ deg) {
    int e = blockIdx.x * 256 + threadIdx.x;
    if (e < N_EDGES) atomicAdd(&deg[dst[e]], 1);
}

// ---------------- exclusive scan, single block ----------------
__global__ __launch_bounds__(1024)
void scan_kernel(const int* __restrict__ deg, int* __restrict__ rowptr, int* __restrict__ cursor) {
    __shared__ int part[1024];
    const int t = threadIdx.x;
    const int base = t * 20;
    int loc[20];
    int sum = 0;
    #pragma unroll
    for (int j = 0; j < 20; ++j) {
        int idx = base + j;
        int v = (idx < N_NODES) ? deg[idx] : 0;
        loc[j] = v;
        sum += v;
    }
    part[t] = sum;
    __syncthreads();
    for (int off = 1; off < 1024; off <<= 1) {
        int v = (t >= off) ? part[t - off] : 0;
        __syncthreads();
        part[t] += v;
        __syncthreads();
    }
    int run = part[t] - sum;
    #pragma unroll
    for (int j = 0; j < 20; ++j) {
        int idx = base + j;
        if (idx < N_NODES) { rowptr[idx] = run; cursor[idx] = run; run += loc[j]; }
    }
    if (t == 0) rowptr[N_NODES] = N_EDGES;
}

// ---------------- CSR position fill: pos[e] = slot of edge e in CSR order ----------------
__global__ __launch_bounds__(256)
void fill_kernel(const int* __restrict__ dst, int* __restrict__ cursor, int* __restrict__ pos) {
    int e = blockIdx.x * 256 + threadIdx.x;
    if (e < N_EDGES) pos[e] = atomicAdd(&cursor[dst[e]], 1);
}

// ---------------- fused edge kernel (8 waves/block, 1 tile of 16 edges per wave) ----------------
// h = elu(ea@w1+b1) via 1 MFMA; msg = (h,1) x W2'' via 34 MFMA, A=W2-frag (LDS),
// B = x-frag (regs, constant over K); h-contraction in VALU. Store row at pos[e] (CSR order).
__global__ __launch_bounds__(512)
void edge_kernel(const float* __restrict__ xin,
                 const float* __restrict__ edge_attr,
                 const int* __restrict__ src,
                 const int* __restrict__ pos,
                 const short* __restrict__ prepL,
                 __hip_bfloat16* __restrict__ msg)
{
    __shared__ __align__(16) short w2s[PREP_SHORTS];   // 35840 B
    __shared__ __align__(16) float h_s[8][16][20];     // 10240 B

    const int t = threadIdx.x;
    for (int i = t; i < PREP_SHORTS / 8; i += 512)
        ((int4*)w2s)[i] = ((const int4*)prepL)[i];
    __syncthreads();

    const int lane = t & 63;
    const int wave = t >> 6;
    const int tile = blockIdx.x * 8 + wave;
    if (tile >= NTILES) return;
    const int eloc = lane & 15;
    const int kg = lane >> 4;
    const int e = tile * 16 + eloc;

    // issue gathers early
    const int sn = src[e];
    const int pe = pos[e];
    const float4 x0 = *(const float4*)(xin + (size_t)sn * 32 + kg * 8);
    const float4 x1 = *(const float4*)(xin + (size_t)sn * 32 + kg * 8 + 4);

    // edge-attr A-fragment: A[m=eloc][k=kg*8+j]; k=16 -> 1.0 (bias), else 0
    bf16x8 af = {0, 0, 0, 0, 0, 0, 0, 0};
    if (kg < 2) {
        const float4 a0 = *(const float4*)(edge_attr + (size_t)e * E_DIM + kg * 8);
        const float4 a1 = *(const float4*)(edge_attr + (size_t)e * E_DIM + kg * 8 + 4);
        af[0] = f2bf(a0.x); af[1] = f2bf(a0.y); af[2] = f2bf(a0.z); af[3] = f2bf(a0.w);
        af[4] = f2bf(a1.x); af[5] = f2bf(a1.y); af[6] = f2bf(a1.z); af[7] = f2bf(a1.w);
    } else if (kg == 2) {
        af[0] = f2bf(1.0f);
    }

    const f32x4 zero4 = {0.f, 0.f, 0.f, 0.f};

    // edge MLP: one MFMA; lane gets h[edge=kg*4+r][k=eloc]; wave-private LDS transpose
    {
        bf16x8 w1f = *(const bf16x8*)&w2s[W2S_SHORTS + lane * 8];
        f32x4 hd = __builtin_amdgcn_mfma_f32_16x16x32_bf16(af, w1f, zero4, 0, 0, 0);
        #pragma unroll
        for (int r = 0; r < 4; ++r)
            h_s[wave][kg * 4 + r][eloc] = elu_f(hd[r]);
    }

    // x B-fragment: B[k=kg*8+j][n=eloc] = x[e][kg*8+j]
    bf16x8 xb;
    xb[0] = f2bf(x0.x); xb[1] = f2bf(x0.y); xb[2] = f2bf(x0.z); xb[3] = f2bf(x0.w);
    xb[4] = f2bf(x1.x); xb[5] = f2bf(x1.y); xb[6] = f2bf(x1.z); xb[7] = f2bf(x1.w);

    // this lane's edge h-row (within-wave DS ordering; compiler inserts lgkmcnt waits)
    float hr[16];
    *(f32x4*)&hr[0]  = *(const f32x4*)&h_s[wave][eloc][0];
    *(f32x4*)&hr[4]  = *(const f32x4*)&h_s[wave][eloc][4];
    *(f32x4*)&hr[8]  = *(const f32x4*)&h_s[wave][eloc][8];
    *(f32x4*)&hr[12] = *(const f32x4*)&h_s[wave][eloc][12];

    float m0[4] = {0, 0, 0, 0}, m1[4] = {0, 0, 0, 0};
    #pragma unroll
    for (int kk = 0; kk < 16; ++kk) {
        bf16x8 a0 = *(const bf16x8*)&w2s[(kk * 2 + 0) * 512 + lane * 8];
        bf16x8 a1 = *(const bf16x8*)&w2s[(kk * 2 + 1) * 512 + lane * 8];
        f32x4 d0 = __builtin_amdgcn_mfma_f32_16x16x32_bf16(a0, xb, zero4, 0, 0, 0);
        f32x4 d1 = __builtin_amdgcn_mfma_f32_16x16x32_bf16(a1, xb, zero4, 0, 0, 0);
        const float hk = hr[kk];
        #pragma unroll
        for (int r = 0; r < 4; ++r) { m0[r] += hk * d0[r]; m1[r] += hk * d1[r]; }
    }
    {   // kk=16: b2 rows (h == 1)
        bf16x8 a0 = *(const bf16x8*)&w2s[(16 * 2 + 0) * 512 + lane * 8];
        bf16x8 a1 = *(const bf16x8*)&w2s[(16 * 2 + 1) * 512 + lane * 8];
        f32x4 d0 = __builtin_amdgcn_mfma_f32_16x16x32_bf16(a0, xb, zero4, 0, 0, 0);
        f32x4 d1 = __builtin_amdgcn_mfma_f32_16x16x32_bf16(a1, xb, zero4, 0, 0, 0);
        #pragma unroll
        for (int r = 0; r < 4; ++r) { m0[r] += d0[r]; m1[r] += d1[r]; }
    }

    // CSR-ordered store: row pe
    short* mp = (short*)(msg + (size_t)pe * D_H);
    short q0[4] = { f2bf(m0[0]), f2bf(m0[1]), f2bf(m0[2]), f2bf(m0[3]) };
    short q1[4] = { f2bf(m1[0]), f2bf(m1[1]), f2bf(m1[2]), f2bf(m1[3]) };
    *(int2*)(mp + kg * 4)      = *(int2*)q0;
    *(int2*)(mp + 16 + kg * 4) = *(int2*)q1;
}

// ---------------- aggregation: wave per node, CONTIGUOUS msg rows + root GEMM + ELU ----------------
template<bool LAST>
__global__ __launch_bounds__(256)
void agg_kernel(const float* __restrict__ xin,
                const __hip_bfloat16* __restrict__ msg,   // CSR-ordered rows
                const int* __restrict__ rowptr,
                const float* __restrict__ root,
                const float* __restrict__ bias,
                const float* __restrict__ cls_w,
                const float* __restrict__ cls_b,
                float* __restrict__ hout,
                float* __restrict__ out)
{
    __shared__ float root_s[32 * 32];
    __shared__ float bias_s[32];
    __shared__ float h2_s[4][33];
    const int t = threadIdx.x;
    for (int i = t; i < 1024; i += 256) root_s[i] = root[i];
    if (t < 32) bias_s[t] = bias[t];
    __syncthreads();

    const int lane = t & 63;
    const int wave = t >> 6;
    const int o = lane & 31;
    const int half = lane >> 5;
    const int n = blockIdx.x * 4 + wave;

    const int start = rowptr[n];
    const int end   = rowptr[n + 1];
    float s = 0.f;
    // halves split rows; rows are contiguous -> two coalesced 64B row-reads in flight
    for (int j = start + half; j < end; j += 2)
        s += bf2f(msg[(size_t)j * D_H + o]);
    s += __shfl_xor(s, 32);

    float acc = s * (1.f / fmaxf((float)(end - start), 1.f)) + bias_s[o];
    const float xv = xin[(size_t)n * 32 + o];
    #pragma unroll
    for (int i = 0; i < 32; ++i)
        acc += __shfl(xv, half * 32 + i) * root_s[i * 32 + o];
    acc = elu_f(acc);

    if (!LAST) {
        if (half == 0) hout[(size_t)n * 32 + o] = acc;
    } else {
        if (half == 0) h2_s[wave][o] = acc;
        __syncthreads();
        if (t < 32) {
            const int nn = t >> 3, j = t & 7;
            float a = cls_b[j];
            #pragma unroll
            for (int i = 0; i < 32; ++i) a += h2_s[nn][i] * cls_w[i * 8 + j];
            out[(size_t)(blockIdx.x * 4 + nn) * D_H / 4 + j] = a;  // n*8 + j
        }
    }
}

extern "C" void kernel_launch(void* const* d_in, const int* in_sizes, int n_in,
                              void* d_out, int out_size, void* d_ws, size_t ws_size,
                              hipStream_t stream)
{
    const float* x          = (const float*)d_in[0];
    const float* edge_attr  = (const float*)d_in[1];
    const int*   edge_index = (const int*)d_in[2];
    const float* w1_0 = (const float*)d_in[3];
    const float* b1_0 = (const float*)d_in[4];
    const float* w2_0 = (const float*)d_in[5];
    const float* b2_0 = (const float*)d_in[6];
    const float* root_0 = (const float*)d_in[7];
    const float* bias_0 = (const float*)d_in[8];
    const float* w1_1 = (const float*)d_in[9];
    const float* b1_1 = (const float*)d_in[10];
    const float* w2_1 = (const float*)d_in[11];
    const float* b2_1 = (const float*)d_in[12];
    const float* root_1 = (const float*)d_in[13];
    const float* bias_1 = (const float*)d_in[14];
    const float* cls_w = (const float*)d_in[15];
    const float* cls_b = (const float*)d_in[16];

    const int* src = edge_index;
    const int* dst = edge_index + N_EDGES;

    char* ws = (char*)d_ws;
    int* deg    = (int*)ws;                            // 20000
    int* rowptr = deg + N_NODES;                       // 20001
    int* cursor = rowptr + N_NODES + 1;                // 20000
    int* pos    = cursor + N_NODES;                    // 200000
    size_t off = ((size_t)(3 * N_NODES + 1 + N_EDGES) * 4 + 15) & ~(size_t)15;
    short* prep = (short*)(ws + off);                  // 2 x 17920 shorts
    off = (off + (size_t)2 * PREP_SHORTS * 2 + 15) & ~(size_t)15;
    __hip_bfloat16* msg = (__hip_bfloat16*)(ws + off); // E*32 bf16 = 12.8 MB
    off = (off + (size_t)N_EDGES * D_H * 2 + 15) & ~(size_t)15;
    float* hbuf = (float*)(ws + off);                  // N*32 f32

    const int EB = (N_EDGES + 255) / 256;       // 782
    const int IB = (2 * PREP_SHORTS + 255) / 256; // 140 (covers N_NODES too)
    const int GB = (NTILES + 7) / 8;            // 1563

    init_kernel<<<IB, 256, 0, stream>>>(w2_0, b2_0, w1_0, b1_0,
                                        w2_1, b2_1, w1_1, b1_1, deg, prep);
    deg_kernel<<<EB, 256, 0, stream>>>(dst, deg);
    scan_kernel<<<1, 1024, 0, stream>>>(deg, rowptr, cursor);
    fill_kernel<<<EB, 256, 0, stream>>>(dst, cursor, pos);

    // layer 0
    edge_kernel<<<GB, 512, 0, stream>>>(x, edge_attr, src, pos, prep, msg);
    agg_kernel<false><<<N_NODES / 4, 256, 0, stream>>>(x, msg, rowptr, root_0, bias_0,
                                                       nullptr, nullptr, hbuf, nullptr);
    // layer 1 (+ fused classifier)
    edge_kernel<<<GB, 512, 0, stream>>>(hbuf, edge_attr, src, pos,
                                        prep + PREP_SHORTS, msg);
    agg_kernel<true><<<N_NODES / 4, 256, 0, stream>>>(hbuf, msg, rowptr, root_1, bias_1,
                                                      cls_w, cls_b, nullptr, (float*)d_out);
}